// Round 5
// baseline (410.347 us; speedup 1.0000x reference)
//
#include <hip/hip_runtime.h>
#include <math.h>

// Problem: N=8192 nodes, D=256 features, H=64 hidden.
// out = [h_out (N*D floats), e (N floats)] concatenated, fp32.
// d_ws holds g[j,:] = e[j] * h[j,:]  (N*D floats = 8 MB) — written by gate_kernel.

typedef float nfloat4 __attribute__((ext_vector_type(4)));

// ---------------- Kernel 1: gate + pre-scale --------------------------------
// e = sigmoid(relu(h@W1+b1)@W2+b2); g[i,:] = e[i]*h[i,:]
// Block = 256 threads (4 waves), stages W1 (64 KB) in LDS; wave handles 4 of
// the block's 16 rows; lane k owns hidden unit k.
__global__ __launch_bounds__(256) void gate_kernel(const float* __restrict__ h,
                                                   const float* __restrict__ W1,
                                                   const float* __restrict__ b1,
                                                   const float* __restrict__ W2,
                                                   const float* __restrict__ b2,
                                                   float* __restrict__ e_out,
                                                   float* __restrict__ g_out,
                                                   int N) {
    __shared__ float W1s[256 * 64];            // 64 KB
    const int tid = threadIdx.x;

    const float4* W1v = reinterpret_cast<const float4*>(W1);
    float4* W1sv = reinterpret_cast<float4*>(W1s);
    #pragma unroll
    for (int t = 0; t < 16; ++t) W1sv[tid + 256 * t] = W1v[tid + 256 * t];
    __syncthreads();

    const int wave = tid >> 6;
    const int k    = tid & 63;                 // hidden unit / float4 slot
    const float b1k = b1[k];
    const float w2k = W2[k];
    const float b2v = b2[0];

    const int base = blockIdx.x * 16;
    for (int r = wave; r < 16; r += 4) {
        const int i = base + r;
        if (i >= N) break;
        const float4* hv = reinterpret_cast<const float4*>(h + (size_t)i * 256);
        float acc = 0.f;
        #pragma unroll 4
        for (int d4 = 0; d4 < 64; ++d4) {
            float4 a = hv[d4];                 // wave-uniform broadcast load
            const int d = d4 * 4;
            acc = fmaf(a.x, W1s[(d + 0) * 64 + k], acc);
            acc = fmaf(a.y, W1s[(d + 1) * 64 + k], acc);
            acc = fmaf(a.z, W1s[(d + 2) * 64 + k], acc);
            acc = fmaf(a.w, W1s[(d + 3) * 64 + k], acc);
        }
        float v = fmaxf(acc + b1k, 0.f) * w2k;
        #pragma unroll
        for (int off = 32; off > 0; off >>= 1) v += __shfl_down(v, off);
        float vs = __shfl(v, 0);               // broadcast the sum to all lanes
        float ev = 1.f / (1.f + expf(-(vs + b2v)));
        if (k == 0) e_out[i] = ev;
        // pre-scaled row: g[i,:] = ev * h[i,:]; lane k writes float4 slot k
        float4 hr = hv[k];
        float4* gv = reinterpret_cast<float4*>(g_out + (size_t)i * 256);
        gv[k] = make_float4(ev * hr.x, ev * hr.y, ev * hr.z, ev * hr.w);
    }
}

// ---------------- Kernel 2: h_out[i,:] = sum_{j: A[i,j]>0} g[j,:] ------------
// One wave per row; lane owns features 4*lane..4*lane+3 (float4 acc).
// A scanned with NON-TEMPORAL float4 loads (zero reuse), prefetched one group
// ahead. All four ballot sub-masks processed in ONE interleaved loop: up to 4
// independent gathers in flight per iteration (branches are wave-uniform).
__global__ __launch_bounds__(256) void agg_kernel(const float* __restrict__ A,
                                                  const float* __restrict__ g,
                                                  float* __restrict__ h_out,
                                                  int N) {
    const int tid  = threadIdx.x;
    const int lane = tid & 63;
    const int i    = blockIdx.x * 4 + (tid >> 6);   // row per wave
    if (i >= N) return;

    const nfloat4* Arow = reinterpret_cast<const nfloat4*>(A + (size_t)i * N);
    const float4*  gv   = reinterpret_cast<const float4*>(g);  // g[j][4d..] = gv[j*64+d]

    float4 acc = {0.f, 0.f, 0.f, 0.f};
    const int groups = N / 256;                     // 32

    nfloat4 a4 = __builtin_nontemporal_load(&Arow[lane]);   // group 0
    for (int gi = 0; gi < groups; ++gi) {
        nfloat4 a_next;
        if (gi + 1 < groups)
            a_next = __builtin_nontemporal_load(&Arow[(gi + 1) * 64 + lane]);

        unsigned long long mx = __ballot(a4.x > 0.f);
        unsigned long long my = __ballot(a4.y > 0.f);
        unsigned long long mz = __ballot(a4.z > 0.f);
        unsigned long long mw = __ballot(a4.w > 0.f);
        const int jb = gi * 256;

        // interleaved: up to 4 independent gathers in flight per pass
        while (mx | my | mz | mw) {
            float4 hx, hy, hz, hw;
            bool px = mx != 0, py = my != 0, pz = mz != 0, pw = mw != 0;
            if (px) { int b = __builtin_ctzll(mx); mx &= mx - 1;
                      hx = gv[(size_t)(jb + 4 * b + 0) * 64 + lane]; }
            if (py) { int b = __builtin_ctzll(my); my &= my - 1;
                      hy = gv[(size_t)(jb + 4 * b + 1) * 64 + lane]; }
            if (pz) { int b = __builtin_ctzll(mz); mz &= mz - 1;
                      hz = gv[(size_t)(jb + 4 * b + 2) * 64 + lane]; }
            if (pw) { int b = __builtin_ctzll(mw); mw &= mw - 1;
                      hw = gv[(size_t)(jb + 4 * b + 3) * 64 + lane]; }
            if (px) { acc.x += hx.x; acc.y += hx.y; acc.z += hx.z; acc.w += hx.w; }
            if (py) { acc.x += hy.x; acc.y += hy.y; acc.z += hy.z; acc.w += hy.w; }
            if (pz) { acc.x += hz.x; acc.y += hz.y; acc.z += hz.z; acc.w += hz.w; }
            if (pw) { acc.x += hw.x; acc.y += hw.y; acc.z += hw.z; acc.w += hw.w; }
        }
        a4 = a_next;
    }

    // write-once output: non-temporal, keep L2 for g
    nfloat4 r; r.x = acc.x; r.y = acc.y; r.z = acc.z; r.w = acc.w;
    nfloat4* outv = reinterpret_cast<nfloat4*>(h_out + (size_t)i * 256);
    __builtin_nontemporal_store(r, &outv[lane]);
}

extern "C" void kernel_launch(void* const* d_in, const int* in_sizes, int n_in,
                              void* d_out, int out_size, void* d_ws, size_t ws_size,
                              hipStream_t stream) {
    const float* A  = (const float*)d_in[0];   // [N, N]
    const float* h  = (const float*)d_in[1];   // [N, D]
    const float* W1 = (const float*)d_in[2];   // [D, H]
    const float* b1 = (const float*)d_in[3];   // [H]
    const float* W2 = (const float*)d_in[4];   // [W2: H,1]
    const float* b2 = (const float*)d_in[5];   // [1]

    const int H = in_sizes[3];                 // 64
    const int D = in_sizes[2] / H;             // 256
    const int N = in_sizes[1] / D;             // 8192

    float* out   = (float*)d_out;
    float* h_out = out;                        // N*D
    float* e_out = out + (size_t)N * D;        // N
    float* g_buf = (float*)d_ws;               // N*D pre-scaled rows

    gate_kernel<<<(N + 15) / 16, 256, 0, stream>>>(h, W1, b1, W2, b2, e_out, g_buf, N);
    agg_kernel<<<(N + 3) / 4, 256, 0, stream>>>(A, g_buf, h_out, N);
}

// Round 6
// 402.130 us; speedup vs baseline: 1.0204x; 1.0204x over previous
//
#include <hip/hip_runtime.h>
#include <math.h>

// Problem: N=8192 nodes, D=256 features, H=64 hidden.
// out = [h_out (N*D floats), e (N floats)] concatenated, fp32.
// d_ws holds g[j,:] = bf16(e[j] * h[j,:])  (N*D bf16 = 4 MB) — fits per-XCD L2.

typedef float nfloat4 __attribute__((ext_vector_type(4)));

__device__ inline float bf16_to_f32(unsigned short s) {
    union { unsigned u; float f; } c; c.u = ((unsigned)s) << 16; return c.f;
}
__device__ inline unsigned short f32_to_bf16(float f) {   // RNE, finite inputs
    union { float f; unsigned u; } c; c.f = f;
    unsigned r = c.u + 0x7FFFu + ((c.u >> 16) & 1u);
    return (unsigned short)(r >> 16);
}

// ---------------- Kernel 1: gate + bf16 pre-scale ----------------------------
// e = sigmoid(relu(h@W1+b1)@W2+b2); g[i,:] = bf16(e[i]*h[i,:])
// Block = 256 threads (4 waves), stages W1 (64 KB) in LDS; wave handles 4 of
// the block's 16 rows; lane k owns hidden unit k / float4 feature slot k.
__global__ __launch_bounds__(256) void gate_kernel(const float* __restrict__ h,
                                                   const float* __restrict__ W1,
                                                   const float* __restrict__ b1,
                                                   const float* __restrict__ W2,
                                                   const float* __restrict__ b2,
                                                   float* __restrict__ e_out,
                                                   unsigned short* __restrict__ g_out,
                                                   int N) {
    __shared__ float W1s[256 * 64];            // 64 KB
    const int tid = threadIdx.x;

    const float4* W1v = reinterpret_cast<const float4*>(W1);
    float4* W1sv = reinterpret_cast<float4*>(W1s);
    #pragma unroll
    for (int t = 0; t < 16; ++t) W1sv[tid + 256 * t] = W1v[tid + 256 * t];
    __syncthreads();

    const int wave = tid >> 6;
    const int k    = tid & 63;
    const float b1k = b1[k];
    const float w2k = W2[k];
    const float b2v = b2[0];

    const int base = blockIdx.x * 16;
    for (int r = wave; r < 16; r += 4) {
        const int i = base + r;
        if (i >= N) break;
        const float4* hv = reinterpret_cast<const float4*>(h + (size_t)i * 256);
        float acc = 0.f;
        #pragma unroll 4
        for (int d4 = 0; d4 < 64; ++d4) {
            float4 a = hv[d4];                 // wave-uniform broadcast load
            const int d = d4 * 4;
            acc = fmaf(a.x, W1s[(d + 0) * 64 + k], acc);
            acc = fmaf(a.y, W1s[(d + 1) * 64 + k], acc);
            acc = fmaf(a.z, W1s[(d + 2) * 64 + k], acc);
            acc = fmaf(a.w, W1s[(d + 3) * 64 + k], acc);
        }
        float v = fmaxf(acc + b1k, 0.f) * w2k;
        #pragma unroll
        for (int off = 32; off > 0; off >>= 1) v += __shfl_down(v, off);
        float vs = __shfl(v, 0);
        float ev = 1.f / (1.f + expf(-(vs + b2v)));
        if (k == 0) e_out[i] = ev;
        // g[i, 4k..4k+3] = bf16(ev * h[i, 4k..4k+3])  (8 B/lane store)
        float4 hr = hv[k];
        ushort4 p;
        p.x = f32_to_bf16(ev * hr.x);
        p.y = f32_to_bf16(ev * hr.y);
        p.z = f32_to_bf16(ev * hr.z);
        p.w = f32_to_bf16(ev * hr.w);
        reinterpret_cast<ushort4*>(g_out + (size_t)i * 256)[k] = p;
    }
}

// ---------------- Kernel 2: h_out[i,:] = sum_{j: A[i,j]>0} g[j,:] ------------
// One wave per row; lane owns features 4*lane..4*lane+3 (fp32 float4 acc).
// A scanned with NON-TEMPORAL float4 loads (zero reuse, evict-first -> doesn't
// displace the 4 MB bf16 g from L2), prefetched one group ahead. Four ballot
// sub-masks processed in one interleaved loop (wave-uniform branches); each
// gather is a 512 B/wave bf16 row read, expected L2-resident.
__global__ __launch_bounds__(256) void agg_kernel(const float* __restrict__ A,
                                                  const unsigned short* __restrict__ g,
                                                  float* __restrict__ h_out,
                                                  int N) {
    const int tid  = threadIdx.x;
    const int lane = tid & 63;
    const int i    = blockIdx.x * 4 + (tid >> 6);   // row per wave
    if (i >= N) return;

    const nfloat4* Arow = reinterpret_cast<const nfloat4*>(A + (size_t)i * N);
    const ushort4* gv   = reinterpret_cast<const ushort4*>(g);  // g[j][4d..] = gv[j*64+d]

    float4 acc = {0.f, 0.f, 0.f, 0.f};
    const int groups = N / 256;                     // 32

    nfloat4 a4 = __builtin_nontemporal_load(&Arow[lane]);   // group 0
    for (int gi = 0; gi < groups; ++gi) {
        nfloat4 a_next;
        if (gi + 1 < groups)
            a_next = __builtin_nontemporal_load(&Arow[(gi + 1) * 64 + lane]);

        unsigned long long mx = __ballot(a4.x > 0.f);
        unsigned long long my = __ballot(a4.y > 0.f);
        unsigned long long mz = __ballot(a4.z > 0.f);
        unsigned long long mw = __ballot(a4.w > 0.f);
        const int jb = gi * 256;

        while (mx | my | mz | mw) {
            ushort4 ux, uy, uz, uw;
            bool px = mx != 0, py = my != 0, pz = mz != 0, pw = mw != 0;
            if (px) { int b = __builtin_ctzll(mx); mx &= mx - 1;
                      ux = gv[(size_t)(jb + 4 * b + 0) * 64 + lane]; }
            if (py) { int b = __builtin_ctzll(my); my &= my - 1;
                      uy = gv[(size_t)(jb + 4 * b + 1) * 64 + lane]; }
            if (pz) { int b = __builtin_ctzll(mz); mz &= mz - 1;
                      uz = gv[(size_t)(jb + 4 * b + 2) * 64 + lane]; }
            if (pw) { int b = __builtin_ctzll(mw); mw &= mw - 1;
                      uw = gv[(size_t)(jb + 4 * b + 3) * 64 + lane]; }
            if (px) { acc.x += bf16_to_f32(ux.x); acc.y += bf16_to_f32(ux.y);
                      acc.z += bf16_to_f32(ux.z); acc.w += bf16_to_f32(ux.w); }
            if (py) { acc.x += bf16_to_f32(uy.x); acc.y += bf16_to_f32(uy.y);
                      acc.z += bf16_to_f32(uy.z); acc.w += bf16_to_f32(uy.w); }
            if (pz) { acc.x += bf16_to_f32(uz.x); acc.y += bf16_to_f32(uz.y);
                      acc.z += bf16_to_f32(uz.z); acc.w += bf16_to_f32(uz.w); }
            if (pw) { acc.x += bf16_to_f32(uw.x); acc.y += bf16_to_f32(uw.y);
                      acc.z += bf16_to_f32(uw.z); acc.w += bf16_to_f32(uw.w); }
        }
        a4 = a_next;
    }

    // write-once output: non-temporal, keep L2 for g
    nfloat4 r; r.x = acc.x; r.y = acc.y; r.z = acc.z; r.w = acc.w;
    nfloat4* outv = reinterpret_cast<nfloat4*>(h_out + (size_t)i * 256);
    __builtin_nontemporal_store(r, &outv[lane]);
}

extern "C" void kernel_launch(void* const* d_in, const int* in_sizes, int n_in,
                              void* d_out, int out_size, void* d_ws, size_t ws_size,
                              hipStream_t stream) {
    const float* A  = (const float*)d_in[0];   // [N, N]
    const float* h  = (const float*)d_in[1];   // [N, D]
    const float* W1 = (const float*)d_in[2];   // [D, H]
    const float* b1 = (const float*)d_in[3];   // [H]
    const float* W2 = (const float*)d_in[4];   // [H, 1]
    const float* b2 = (const float*)d_in[5];   // [1]

    const int H = in_sizes[3];                 // 64
    const int D = in_sizes[2] / H;             // 256
    const int N = in_sizes[1] / D;             // 8192

    float* out   = (float*)d_out;
    float* h_out = out;                        // N*D
    float* e_out = out + (size_t)N * D;        // N
    unsigned short* g_buf = (unsigned short*)d_ws;  // N*D bf16 pre-scaled rows (4 MB)

    gate_kernel<<<(N + 15) / 16, 256, 0, stream>>>(h, W1, b1, W2, b2, e_out, g_buf, N);
    agg_kernel<<<(N + 3) / 4, 256, 0, stream>>>(A, g_buf, h_out, N);
}